// Round 1
// baseline (3977.348 us; speedup 1.0000x reference)
//
#include <hip/hip_runtime.h>
#include <math.h>

// GCN generator: B=8, N=F=128.
// One block per batch, 1024 threads, 128 sequential steps inside the kernel.
// LDS: G (adjacency carry, 64KB) + x (features, 64KB; reused for y) +
//      W chunk (16KB) + prob/d vectors. Total ~145KB (needs dyn-LDS opt-in).
// fp32 throughout for round-1 correctness baseline.

#define NN 128
#define EPSF 1e-8f

__global__ __launch_bounds__(1024)
void gcn_gen_kernel(const float* __restrict__ gx,
                    const float* __restrict__ gW,
                    const float* __restrict__ gb,
                    float* __restrict__ gout)
{
    extern __shared__ float lds[];
    float* s_G    = lds;                 // 128*128 adjacency (normalized carry)
    float* s_x    = lds + NN * NN;       // 128*128 features; reused for y
    float* s_Wc   = lds + 2 * NN * NN;   // 32*128 W chunk
    float* s_prob = s_Wc + 32 * NN;      // 128
    float* s_d    = s_prob + NN;         // 128

    const int b  = blockIdx.x;
    const int t  = threadIdx.x;
    const int ct = t & 31;               // column tile (4 cols each)
    const int rt = t >> 5;               // row tile (4 rows each)
    const int c0 = ct * 4;
    const int r0 = rt * 4;
    const int j8 = t >> 3;               // row owner for 8-thread reductions
    const int s8 = t & 7;

    const float* xb  = gx + (size_t)b * NN * NN;
    float* outb      = gout + (size_t)b * NN * NN;

    // init: load x into LDS, G = I, out = I
    #pragma unroll
    for (int q = 0; q < 4; ++q) {
        int idx = q * 4096 + t * 4;
        int row = idx >> 7;
        int col = idx & 127;
        float4 xv = *(const float4*)(xb + idx);
        *(float4*)(s_x + idx) = xv;
        float4 e;
        e.x = (col + 0 == row) ? 1.f : 0.f;
        e.y = (col + 1 == row) ? 1.f : 0.f;
        e.z = (col + 2 == row) ? 1.f : 0.f;
        e.w = (col + 3 == row) ? 1.f : 0.f;
        *(float4*)(s_G + idx) = e;
        *(float4*)(outb + idx) = e;
    }
    const float4 bv = *(const float4*)(gb + c0);
    __syncthreads();

    for (int i = 0; i < NN; ++i) {
        if (i > 0) {
            // prob[j] = sigmoid(0.5 * dot(x[j], x[i]))  (x = pre-update x)
            float p = 0.f;
            const float* xj = s_x + j8 * NN + s8 * 16;
            const float* xi = s_x + i  * NN + s8 * 16;
            #pragma unroll
            for (int q = 0; q < 4; ++q) {
                float4 a = *(const float4*)(xj + q * 4);
                float4 c = *(const float4*)(xi + q * 4);
                p += a.x * c.x + a.y * c.y + a.z * c.z + a.w * c.w;
            }
            p += __shfl_xor(p, 1);
            p += __shfl_xor(p, 2);
            p += __shfl_xor(p, 4);
            if (s8 == 0)
                s_prob[j8] = 1.f / (1.f + expf(-0.5f * p));
            __syncthreads();
            // set row/col i (j < i) in G (carry) and in global output
            if (t < i) {
                float pv = s_prob[t];
                s_G[i * NN + t] = pv;
                s_G[t * NN + i] = pv;
                outb[i * NN + t] = pv;
                outb[t * NN + i] = pv;
            }
            __syncthreads();
        }

        // deg_j = 1 + sum_k G[j][k];  d_j = rsqrt(deg + eps)
        {
            float dsum = 0.f;
            const float* Gj = s_G + j8 * NN + s8 * 16;
            #pragma unroll
            for (int q = 0; q < 4; ++q) {
                float4 a = *(const float4*)(Gj + q * 4);
                dsum += a.x + a.y + a.z + a.w;
            }
            dsum += __shfl_xor(dsum, 1);
            dsum += __shfl_xor(dsum, 2);
            dsum += __shfl_xor(dsum, 4);
            if (s8 == 0)
                s_d[j8] = 1.f / sqrtf(dsum + 1.0f + EPSF);
        }
        __syncthreads();

        // G = d .* (G + I) .* d   (in place, stays symmetric)
        #pragma unroll
        for (int q = 0; q < 4; ++q) {
            int idx = q * 4096 + t * 4;
            int row = idx >> 7;
            int col = idx & 127;
            float dr = s_d[row];
            float4 v = *(float4*)(s_G + idx);
            v.x = (v.x + ((col + 0 == row) ? 1.f : 0.f)) * dr * s_d[col + 0];
            v.y = (v.y + ((col + 1 == row) ? 1.f : 0.f)) * dr * s_d[col + 1];
            v.z = (v.z + ((col + 2 == row) ? 1.f : 0.f)) * dr * s_d[col + 2];
            v.w = (v.w + ((col + 3 == row) ? 1.f : 0.f)) * dr * s_d[col + 3];
            *(float4*)(s_G + idx) = v;
        }
        __syncthreads();

        // y = G @ x ; per-thread 4x4 tile. G symmetric: G[r][k] = G[k][r]
        float acc[4][4] = {{0.f}};
        #pragma unroll 2
        for (int k = 0; k < NN; ++k) {
            float4 av = *(const float4*)(s_G + k * NN + r0);  // G[r0..3][k]
            float4 xv = *(const float4*)(s_x + k * NN + c0);
            #pragma unroll
            for (int a = 0; a < 4; ++a) {
                float aa = ((const float*)&av)[a];
                acc[a][0] += aa * xv.x;
                acc[a][1] += aa * xv.y;
                acc[a][2] += aa * xv.z;
                acc[a][3] += aa * xv.w;
            }
        }
        __syncthreads();

        // x no longer needed this step: stash y into s_x (row-major)
        #pragma unroll
        for (int a = 0; a < 4; ++a) {
            float4 v = make_float4(acc[a][0], acc[a][1], acc[a][2], acc[a][3]);
            *(float4*)(s_x + (r0 + a) * NN + c0) = v;
        }
        __syncthreads();

        // z = y @ W, staging W in 32-row chunks through LDS
        float z[4][4] = {{0.f}};
        for (int kc = 0; kc < 4; ++kc) {
            {
                int idx = t * 4;  // 1024 threads * 4 floats = 32*128 chunk
                float4 wv = *(const float4*)(gW + kc * 32 * NN + idx);
                *(float4*)(s_Wc + idx) = wv;
            }
            __syncthreads();
            #pragma unroll 2
            for (int k4 = 0; k4 < 8; ++k4) {
                float4 yv[4];
                #pragma unroll
                for (int a = 0; a < 4; ++a)
                    yv[a] = *(const float4*)(s_x + (r0 + a) * NN + kc * 32 + k4 * 4);
                #pragma unroll
                for (int e = 0; e < 4; ++e) {
                    float4 wv = *(const float4*)(s_Wc + (k4 * 4 + e) * NN + c0);
                    #pragma unroll
                    for (int a = 0; a < 4; ++a) {
                        float ya = ((const float*)&yv[a])[e];
                        z[a][0] += ya * wv.x;
                        z[a][1] += ya * wv.y;
                        z[a][2] += ya * wv.z;
                        z[a][3] += ya * wv.w;
                    }
                }
            }
            __syncthreads();
        }

        // bias + relu
        #pragma unroll
        for (int a = 0; a < 4; ++a) {
            z[a][0] = fmaxf(z[a][0] + bv.x, 0.f);
            z[a][1] = fmaxf(z[a][1] + bv.y, 0.f);
            z[a][2] = fmaxf(z[a][2] + bv.z, 0.f);
            z[a][3] = fmaxf(z[a][3] + bv.w, 0.f);
        }
        // row-normalize (scan steps only, not the pre-scan update)
        float rn[4] = {1.f, 1.f, 1.f, 1.f};
        if (i > 0) {
            #pragma unroll
            for (int a = 0; a < 4; ++a) {
                float ss = z[a][0]*z[a][0] + z[a][1]*z[a][1]
                         + z[a][2]*z[a][2] + z[a][3]*z[a][3];
                ss += __shfl_xor(ss, 1);
                ss += __shfl_xor(ss, 2);
                ss += __shfl_xor(ss, 4);
                ss += __shfl_xor(ss, 8);
                ss += __shfl_xor(ss, 16);
                rn[a] = 1.f / (sqrtf(ss) + 1e-8f);
            }
        }
        // write new x
        #pragma unroll
        for (int a = 0; a < 4; ++a) {
            float4 v = make_float4(z[a][0]*rn[a], z[a][1]*rn[a],
                                   z[a][2]*rn[a], z[a][3]*rn[a]);
            *(float4*)(s_x + (r0 + a) * NN + c0) = v;
        }
        __syncthreads();
    }
}

extern "C" void kernel_launch(void* const* d_in, const int* in_sizes, int n_in,
                              void* d_out, int out_size, void* d_ws, size_t ws_size,
                              hipStream_t stream) {
    const float* x  = (const float*)d_in[0];
    const float* W  = (const float*)d_in[1];
    const float* bb = (const float*)d_in[2];
    float* out = (float*)d_out;

    const size_t shmem = (size_t)(2 * NN * NN + 32 * NN + 2 * NN) * sizeof(float);
    hipFuncSetAttribute((const void*)gcn_gen_kernel,
                        hipFuncAttributeMaxDynamicSharedMemorySize, (int)shmem);
    gcn_gen_kernel<<<8, 1024, shmem, stream>>>(x, W, bb, out);
}

// Round 2
// 2258.500 us; speedup vs baseline: 1.7611x; 1.7611x over previous
//
#include <hip/hip_runtime.h>
#include <math.h>

// GCN generator: B=8, N=F=128. One block/batch, 1024 threads (16 waves),
// 128 sequential steps in-kernel. Matmuls via f16-pair (hi + lo*2^-11) MFMA
// 16x16x32, 3 passes (hi*hi into acc; hi*lo + lo*hi into scaled cc).
// G and x carried as f16 hi/lo pairs in LDS ([128][136] padded rows).
// Edge probs derived from mm2 output fragments (zdot/norms) - no strided pass.

#define NN 128
#define SP 136
#define KSC 2048.0f
#define KINV 4.8828125e-4f

typedef _Float16 f16;
typedef _Float16 f16x8 __attribute__((ext_vector_type(8)));
typedef _Float16 f16x4 __attribute__((ext_vector_type(4)));
typedef float f32x4 __attribute__((ext_vector_type(4)));

__device__ __forceinline__ f32x4 mm(f16x8 a, f16x8 b, f32x4 c) {
    return __builtin_amdgcn_mfma_f32_16x16x32_f16(a, b, c, 0, 0, 0);
}

__global__ __launch_bounds__(1024)
void gcn_gen_kernel(const float* __restrict__ gx,
                    const float* __restrict__ gW,
                    const float* __restrict__ gb,
                    float* __restrict__ gout)
{
    extern __shared__ char lds_raw[];
    f16* G_hi = (f16*)lds_raw;                 // [128][136] adjacency hi
    f16* G_lo = G_hi + NN*SP;                  // adjacency lo (scaled 2048)
    f16* X_hi = G_lo + NN*SP;                  // xT [f][n]  (also y [n][f])
    f16* X_lo = X_hi + NN*SP;
    float* s_prob = (float*)(X_lo + NN*SP);    // [128]
    float* s_d    = s_prob + NN;               // [128] rsqrt degrees
    float* s_zrow = s_d + NN;                  // [128] pivot z row
    float* s_ssq  = s_zrow + NN;               // [4][128] ssq partials by wc
    float* s_pdt  = s_ssq + 4*NN;              // [4][128] zdot partials by wc

    const int b = blockIdx.x;
    const int t = threadIdx.x;
    const int lane = t & 63;
    const int w = t >> 6;                      // wave 0..15
    const int wr = w >> 2, wc = w & 3;         // wave grid 4x4 (32x32/wave)
    const int lrow = lane & 15;                // frag row/col within 16
    const int lgrp = lane >> 4;                // k-group 0..3
    const int j8 = t >> 3, s8 = t & 7;         // 8 threads per matrix row

    const float* xb = gx + (size_t)b*NN*NN;
    float* outb = gout + (size_t)b*NN*NN;

    const float bias0 = gb[wc*32 + lrow];
    const float bias1 = gb[wc*32 + 16 + lrow];

    // ---- init: G = I (pairs), out = eye, X = split(x^T) ----
    for (int q = 0; q < 16; ++q) {
        int idx = q*1024 + t;
        int r = idx >> 7, c = idx & 127;
        float e = (r == c) ? 1.f : 0.f;
        G_hi[r*SP + c] = (f16)e;
        G_lo[r*SP + c] = (f16)0.f;
        outb[idx] = e;
        float v = xb[idx];                     // x[n=r][f=c]
        f16 h = (f16)v;
        X_hi[c*SP + r] = h;
        X_lo[c*SP + r] = (f16)((v - (float)h)*KSC);
    }
    __syncthreads();

    for (int i = 0; i < NN; ++i) {
        const int piv = (i + 1) & 127;
        // ---- A: G row/col i <- prob, out writes ----
        if (i > 0) {
            if (t < i) {
                float p = s_prob[t];
                f16 h = (f16)p;
                f16 l = (f16)((p - (float)h)*KSC);
                G_hi[i*SP + t] = h;  G_lo[i*SP + t] = l;
                G_hi[t*SP + i] = h;  G_lo[t*SP + i] = l;
                outb[i*NN + t] = p;
                outb[t*NN + i] = p;
            }
            __syncthreads();
        }
        // ---- B: degrees ----
        {
            const f16x8* ph = (const f16x8*)(G_hi + j8*SP + s8*16);
            const f16x8* pl = (const f16x8*)(G_lo + j8*SP + s8*16);
            f16x8 h0 = ph[0], h1 = ph[1], l0 = pl[0], l1 = pl[1];
            float s = 0.f;
            #pragma unroll
            for (int e = 0; e < 8; ++e)
                s += (float)h0[e] + (float)h1[e]
                   + ((float)l0[e] + (float)l1[e]) * KINV;
            s += __shfl_xor(s, 1);
            s += __shfl_xor(s, 2);
            s += __shfl_xor(s, 4);
            if (s8 == 0) s_d[j8] = 1.f / sqrtf(s + 1.0f + 1e-8f);
        }
        __syncthreads();
        // ---- C: G = d .* (G + I) .* d, re-split ----
        {
            const int row = j8, c0 = s8*16;
            const float dr = s_d[row];
            float dc[16];
            #pragma unroll
            for (int q = 0; q < 4; ++q)
                *(float4*)(dc + 4*q) = *(const float4*)(s_d + c0 + 4*q);
            f16x8* ph = (f16x8*)(G_hi + row*SP + c0);
            f16x8* pl = (f16x8*)(G_lo + row*SP + c0);
            f16x8 h[2] = {ph[0], ph[1]};
            f16x8 l[2] = {pl[0], pl[1]};
            #pragma unroll
            for (int half = 0; half < 2; ++half) {
                #pragma unroll
                for (int e = 0; e < 8; ++e) {
                    int c = c0 + half*8 + e;
                    float g = (float)h[half][e] + (float)l[half][e]*KINV;
                    g += (c == row) ? 1.f : 0.f;
                    g *= dr * dc[half*8 + e];
                    f16 hh = (f16)g;
                    h[half][e] = hh;
                    l[half][e] = (f16)((g - (float)hh)*KSC);
                }
            }
            ph[0] = h[0]; ph[1] = h[1];
            pl[0] = l[0]; pl[1] = l[1];
        }
        __syncthreads();

        // ---- D: mm1  y = G @ x ----
        f32x4 acc[2][2], cc[2][2];
        #pragma unroll
        for (int rt = 0; rt < 2; ++rt)
            #pragma unroll
            for (int ct = 0; ct < 2; ++ct) {
                acc[rt][ct] = (f32x4){0.f,0.f,0.f,0.f};
                cc[rt][ct]  = (f32x4){0.f,0.f,0.f,0.f};
            }
        #pragma unroll
        for (int ks = 0; ks < 4; ++ks) {
            const int ko = ks*32 + lgrp*8;
            f16x8 Bh[2], Bl[2];
            #pragma unroll
            for (int ct = 0; ct < 2; ++ct) {
                int col = wc*32 + ct*16 + lrow;        // f
                Bh[ct] = *(const f16x8*)(X_hi + col*SP + ko);
                Bl[ct] = *(const f16x8*)(X_lo + col*SP + ko);
            }
            #pragma unroll
            for (int rt = 0; rt < 2; ++rt) {
                int row = wr*32 + rt*16 + lrow;        // n
                f16x8 Ah = *(const f16x8*)(G_hi + row*SP + ko);
                f16x8 Al = *(const f16x8*)(G_lo + row*SP + ko);
                #pragma unroll
                for (int ct = 0; ct < 2; ++ct) {
                    acc[rt][ct] = mm(Ah, Bh[ct], acc[rt][ct]);
                    cc[rt][ct]  = mm(Ah, Bl[ct], cc[rt][ct]);
                    cc[rt][ct]  = mm(Al, Bh[ct], cc[rt][ct]);
                }
            }
        }
        __syncthreads();                                // mm1 LDS reads done
        // ---- E: y -> X buffers, row-major [n][f] pairs ----
        #pragma unroll
        for (int rt = 0; rt < 2; ++rt)
        #pragma unroll
        for (int ct = 0; ct < 2; ++ct) {
            int col = wc*32 + ct*16 + lrow;
            #pragma unroll
            for (int q = 0; q < 4; ++q) {
                int row = wr*32 + rt*16 + lgrp*4 + q;
                float v = acc[rt][ct][q] + cc[rt][ct][q]*KINV;
                f16 h = (f16)v;
                X_hi[row*SP + col] = h;
                X_lo[row*SP + col] = (f16)((v - (float)h)*KSC);
            }
        }
        __syncthreads();
        // ---- F: mm2  z = y @ W  (W split from global fp32, L2-hot) ----
        #pragma unroll
        for (int rt = 0; rt < 2; ++rt)
            #pragma unroll
            for (int ct = 0; ct < 2; ++ct) {
                acc[rt][ct] = (f32x4){0.f,0.f,0.f,0.f};
                cc[rt][ct]  = (f32x4){0.f,0.f,0.f,0.f};
            }
        #pragma unroll
        for (int ks = 0; ks < 4; ++ks) {
            const int ko = ks*32 + lgrp*8;
            f16x8 Bh[2], Bl[2];
            #pragma unroll
            for (int ct = 0; ct < 2; ++ct) {
                int col = wc*32 + ct*16 + lrow;        // f_out
                #pragma unroll
                for (int r = 0; r < 8; ++r) {
                    float wv = gW[(ko + r)*NN + col];
                    f16 h = (f16)wv;
                    Bh[ct][r] = h;
                    Bl[ct][r] = (f16)((wv - (float)h)*KSC);
                }
            }
            #pragma unroll
            for (int rt = 0; rt < 2; ++rt) {
                int row = wr*32 + rt*16 + lrow;        // n
                f16x8 Ah = *(const f16x8*)(X_hi + row*SP + ko);
                f16x8 Al = *(const f16x8*)(X_lo + row*SP + ko);
                #pragma unroll
                for (int ct = 0; ct < 2; ++ct) {
                    acc[rt][ct] = mm(Ah, Bh[ct], acc[rt][ct]);
                    cc[rt][ct]  = mm(Ah, Bl[ct], cc[rt][ct]);
                    cc[rt][ct]  = mm(Al, Bh[ct], cc[rt][ct]);
                }
            }
        }
        // ---- epilogue in regs: bias + relu, ssq partials, pivot row ----
        float z[2][2][4];
        #pragma unroll
        for (int rt = 0; rt < 2; ++rt)
        #pragma unroll
        for (int ct = 0; ct < 2; ++ct)
        #pragma unroll
        for (int q = 0; q < 4; ++q)
            z[rt][ct][q] = fmaxf(acc[rt][ct][q] + cc[rt][ct][q]*KINV
                                 + (ct ? bias1 : bias0), 0.f);
        float ss[8];
        #pragma unroll
        for (int k = 0; k < 8; ++k) {
            float a = z[k>>2][0][k&3], c2 = z[k>>2][1][k&3];
            ss[k] = a*a + c2*c2;
        }
        #pragma unroll
        for (int k = 0; k < 8; ++k) {
            ss[k] += __shfl_xor(ss[k], 1);
            ss[k] += __shfl_xor(ss[k], 2);
            ss[k] += __shfl_xor(ss[k], 4);
            ss[k] += __shfl_xor(ss[k], 8);
        }
        if (lrow == 0) {
            #pragma unroll
            for (int k = 0; k < 8; ++k) {
                int row = wr*32 + (k>>2)*16 + lgrp*4 + (k&3);
                s_ssq[wc*NN + row] = ss[k];
            }
        }
        if (wr == (piv>>5) && lgrp == ((piv>>2)&3)) {
            int prt = (piv>>4)&1, pq = piv&3;
            s_zrow[wc*32 + lrow]      = z[prt][0][pq];
            s_zrow[wc*32 + 16 + lrow] = z[prt][1][pq];
        }
        __syncthreads();
        // ---- G: normalize + write new x (xT pairs) + zdot partials ----
        float dv[8];
        #pragma unroll
        for (int k = 0; k < 8; ++k) {
            int row = wr*32 + (k>>2)*16 + lgrp*4 + (k&3);
            float sq = s_ssq[row] + s_ssq[NN+row] + s_ssq[2*NN+row] + s_ssq[3*NN+row];
            dv[k] = (i == 0) ? 1.f : 1.f/(sqrtf(sq) + 1e-8f);
        }
        #pragma unroll
        for (int rt = 0; rt < 2; ++rt)
        #pragma unroll
        for (int ct = 0; ct < 2; ++ct) {
            int col = wc*32 + ct*16 + lrow;            // f
            int rowb = wr*32 + rt*16 + lgrp*4;         // n base (4-aligned)
            f16x4 hv, lv;
            #pragma unroll
            for (int q = 0; q < 4; ++q) {
                float v = z[rt][ct][q] * dv[rt*4+q];
                f16 h = (f16)v;
                hv[q] = h;
                lv[q] = (f16)((v - (float)h)*KSC);
            }
            *(f16x4*)(X_hi + col*SP + rowb) = hv;
            *(f16x4*)(X_lo + col*SP + rowb) = lv;
        }
        {
            float zr0 = s_zrow[wc*32 + lrow];
            float zr1 = s_zrow[wc*32 + 16 + lrow];
            float pd[8];
            #pragma unroll
            for (int k = 0; k < 8; ++k)
                pd[k] = z[k>>2][0][k&3]*zr0 + z[k>>2][1][k&3]*zr1;
            #pragma unroll
            for (int k = 0; k < 8; ++k) {
                pd[k] += __shfl_xor(pd[k], 1);
                pd[k] += __shfl_xor(pd[k], 2);
                pd[k] += __shfl_xor(pd[k], 4);
                pd[k] += __shfl_xor(pd[k], 8);
            }
            if (lrow == 0) {
                #pragma unroll
                for (int k = 0; k < 8; ++k) {
                    int row = wr*32 + (k>>2)*16 + lgrp*4 + (k&3);
                    s_pdt[wc*NN + row] = pd[k];
                }
            }
        }
        __syncthreads();
        // ---- H: finalize probs for next step ----
        if (t < NN) {
            float zd  = s_pdt[t] + s_pdt[NN+t] + s_pdt[2*NN+t] + s_pdt[3*NN+t];
            float sqj = s_ssq[t] + s_ssq[NN+t] + s_ssq[2*NN+t] + s_ssq[3*NN+t];
            float sqp = s_ssq[piv] + s_ssq[NN+piv] + s_ssq[2*NN+piv] + s_ssq[3*NN+piv];
            float dj = (i == 0) ? 1.f : 1.f/(sqrtf(sqj) + 1e-8f);
            float dp = (i == 0) ? 1.f : 1.f/(sqrtf(sqp) + 1e-8f);
            float sc = 0.5f * zd * dj * dp;
            s_prob[t] = 1.f/(1.f + expf(-sc));
        }
        __syncthreads();
    }
}

extern "C" void kernel_launch(void* const* d_in, const int* in_sizes, int n_in,
                              void* d_out, int out_size, void* d_ws, size_t ws_size,
                              hipStream_t stream) {
    const float* x  = (const float*)d_in[0];
    const float* W  = (const float*)d_in[1];
    const float* bb = (const float*)d_in[2];
    float* out = (float*)d_out;

    const size_t shmem = (size_t)(4*NN*SP)*sizeof(f16)
                       + (size_t)(3*NN + 8*NN)*sizeof(float);   // 144896 B
    hipFuncSetAttribute((const void*)gcn_gen_kernel,
                        hipFuncAttributeMaxDynamicSharedMemorySize, (int)shmem);
    gcn_gen_kernel<<<8, 1024, shmem, stream>>>(x, W, bb, out);
}